// Round 12
// baseline (247.948 us; speedup 1.0000x reference)
//
#include <hip/hip_runtime.h>
#include <math.h>

#define NP 20000
#define NG 5000
#define NTOT 25000
#define DF 512
#define NCLS 1000
#define DH 128
#define EPP 240000
#define EPG 100000
#define EGP 100000
#define ETOT 440000
#define FS 16   // fill stride (one counter per 64B line)
#define HB 16   // partial-histogram blocks per job

typedef __attribute__((ext_vector_type(8))) __bf16 bf16x8;
typedef __attribute__((ext_vector_type(4))) float f32x4;

__device__ __forceinline__ void gl2lds16(const void* g, void* l) {
    __builtin_amdgcn_global_load_lds(
        (const __attribute__((address_space(1))) unsigned int*)g,
        (__attribute__((address_space(3))) unsigned int*)l, 16, 0, 0);
}

__device__ __forceinline__ float b2f(unsigned short u) {
    union { unsigned int i; float f; } c; c.i = ((unsigned int)u) << 16; return c.f;
}

__device__ __forceinline__ unsigned short f2bbits(float v) {
    __bf16 t = (__bf16)v;
    return __builtin_bit_cast(unsigned short, t);
}

// ---------------- partial histograms: HB blocks/job, LDS-private, plain stores ----------------
__global__ __launch_bounds__(1024) void hist_part_kernel(
    const int* __restrict__ src_pp, const int* __restrict__ dst_pp,
    const int* __restrict__ src_pg, const int* __restrict__ dst_pg,
    const int* __restrict__ src_gp, const int* __restrict__ dst_gp,
    int* __restrict__ partial)
{
    __shared__ int bins[20000];
    const int job = blockIdx.y, b = blockIdx.x;
    const int* idx; int nbins, nedge; size_t pbase;
    switch (job) {
    case 0: idx = src_pp; nbins = 20000; nedge = EPP; pbase = 0;       break;
    case 1: idx = dst_pp; nbins = 20000; nedge = EPP; pbase = 320000;  break;
    case 2: idx = src_pg; nbins = 20000; nedge = EPG; pbase = 640000;  break;
    case 3: idx = dst_pg; nbins = 5000;  nedge = EPG; pbase = 960000;  break;
    case 4: idx = src_gp; nbins = 5000;  nedge = EGP; pbase = 1040000; break;
    default: idx = dst_gp; nbins = 20000; nedge = EGP; pbase = 1120000; break;
    }
    for (int i = threadIdx.x; i < nbins; i += 1024) bins[i] = 0;
    __syncthreads();
    const int chunk = (nedge + HB - 1) / HB;
    const int e0 = b * chunk, e1 = min(e0 + chunk, nedge);
    for (int e = e0 + threadIdx.x; e < e1; e += 1024) atomicAdd(&bins[idx[e]], 1);
    __syncthreads();
    int* dst = partial + pbase + (size_t)b * nbins;
    for (int i = threadIdx.x; i < nbins; i += 1024) dst[i] = bins[i];
}

// ---------------- merge partials -> degree arrays; job 6 zeroes the fill counters ----------------
__global__ __launch_bounds__(256) void hist_merge_kernel(const int* __restrict__ partial,
    int* __restrict__ outdeg_pp, int* __restrict__ indeg_pp,
    int* __restrict__ outdeg_pg, int* __restrict__ indeg_pg,
    int* __restrict__ outdeg_gp, int* __restrict__ indeg_gp,
    int* __restrict__ fill)
{
    const int job = blockIdx.y;
    const int bin = blockIdx.x * 256 + threadIdx.x;
    if (job == 6) {
        if (bin < NTOT * FS) fill[bin] = 0;
        return;
    }
    const int nbins = (job == 3 || job == 4) ? 5000 : 20000;
    if (bin >= nbins) return;
    size_t pbase; int* outp;
    switch (job) {
    case 0: pbase = 0;       outp = outdeg_pp; break;
    case 1: pbase = 320000;  outp = indeg_pp;  break;
    case 2: pbase = 640000;  outp = outdeg_pg; break;
    case 3: pbase = 960000;  outp = indeg_pg;  break;
    case 4: pbase = 1040000; outp = outdeg_gp; break;
    default: pbase = 1120000; outp = indeg_gp; break;
    }
    const int* p = partial + pbase + bin;
    int s = 0;
#pragma unroll
    for (int b = 0; b < HB; b++) s += p[(size_t)b * nbins];
    outp[bin] = s;
}

// ---------------- exclusive scan -> row_ptr[NTOT+1] ----------------
__global__ __launch_bounds__(1024) void scan_kernel(const int* __restrict__ indeg_pp,
                                                    const int* __restrict__ indeg_gp,
                                                    const int* __restrict__ indeg_pg,
                                                    int* __restrict__ row_ptr)
{
    __shared__ int part[1024];
    int t = threadIdx.x;
    const int CH = (NTOT + 1023) / 1024;
    int base = t * CH;
    auto cntf = [&](int idx) -> int {
        return (idx < NP) ? (indeg_pp[idx] + indeg_gp[idx]) : indeg_pg[idx - NP];
    };
    int s = 0;
    for (int i = 0; i < CH; i++) { int idx = base + i; if (idx < NTOT) s += cntf(idx); }
    part[t] = s;
    __syncthreads();
    for (int off = 1; off < 1024; off <<= 1) {
        int v = (t >= off) ? part[t - off] : 0;
        __syncthreads();
        part[t] += v;
        __syncthreads();
    }
    int run = (t == 0) ? 0 : part[t - 1];
    for (int i = 0; i < CH; i++) {
        int idx = base + i;
        if (idx < NTOT) { row_ptr[idx] = run; run += cntf(idx); }
    }
    if (t == 1023) row_ptr[NTOT] = part[1023];
}

// ---------------- scatter edges into CSR ----------------
__global__ void scatter_kernel(const int* __restrict__ src_pp, const int* __restrict__ dst_pp,
                               const int* __restrict__ src_pg, const int* __restrict__ dst_pg,
                               const int* __restrict__ src_gp, const int* __restrict__ dst_gp,
                               const int* __restrict__ outdeg_pp, const int* __restrict__ outdeg_pg,
                               const int* __restrict__ outdeg_gp,
                               const int* __restrict__ row_ptr, int* fill,
                               int2* __restrict__ edata)
{
    int e = blockIdx.x * blockDim.x + threadIdx.x;
    int s, d, t; float sc;
    if (e < EPP) {
        s = src_pp[e]; d = dst_pp[e]; t = 0;
        sc = rsqrtf((float)max(outdeg_pp[s], 1));
    } else if (e < EPP + EPG) {
        int i = e - EPP; s = src_pg[i]; d = NP + dst_pg[i]; t = 1;
        sc = rsqrtf((float)max(outdeg_pg[s], 1));
    } else if (e < ETOT) {
        int i = e - EPP - EPG; int sl = src_gp[i]; s = NP + sl; d = dst_gp[i]; t = 2;
        sc = rsqrtf((float)max(outdeg_gp[sl], 1));
    } else return;
    int pos = row_ptr[d] + atomicAdd(&fill[d * FS], 1);
    edata[pos] = make_int2(s | (t << 16), __float_as_int(sc));
}

// ---------------- fused conversions: x_go and all 8 weights (ranged 1D grid) ----------------
__global__ __launch_bounds__(256) void conv_all_kernel(
    const float* __restrict__ xg,
    const float* W1p, const float* W1g, const float* Wlp, const float* Wrp, const float* Wrg,
    const float* Wnl, const float* Wnr, const float* Wfc,
    __bf16* __restrict__ xgb,
    __bf16* w1pt, __bf16* w1gt, __bf16* wlpt, __bf16* wrpt, __bf16* wrgt,
    __bf16* wnlt, __bf16* wnrt, __bf16* wfct)
{
    const int b = blockIdx.x;
    if (b < 2528) {
        long long e = ((long long)b * 256 + threadIdx.x) * 8;
        int row = (int)(e >> 10), k = (int)(e & 1023);
        __bf16 pk[8];
        if (row < NG && k + 7 < 1000) {
            f32x4 v0 = *(const f32x4*)(xg + (size_t)row * 1000 + k);
            f32x4 v1 = *(const f32x4*)(xg + (size_t)row * 1000 + k + 4);
#pragma unroll
            for (int i = 0; i < 4; i++) { pk[i] = (__bf16)v0[i]; pk[4 + i] = (__bf16)v1[i]; }
        } else {
#pragma unroll
            for (int i = 0; i < 8; i++) {
                int kk = k + i;
                pk[i] = (__bf16)((row < NG && kk < 1000) ? xg[(size_t)row * 1000 + kk] : 0.f);
            }
        }
        *(bf16x8*)(xgb + e) = *(bf16x8*)pk;
        return;
    }
    int wb = b - 2528;
    int e;
    if (wb < 256)      { e = wb * 256 + threadIdx.x;          int n = e >> 9, k = e & 511;  w1pt[e] = (__bf16)W1p[(size_t)k * 128 + n]; }
    else if (wb < 768) { e = (wb - 256) * 256 + threadIdx.x;  int n = e >> 10, k = e & 1023; w1gt[e] = (__bf16)(k < 1000 ? W1g[(size_t)k * 128 + n] : 0.f); }
    else if (wb < 832) { e = (wb - 768) * 256 + threadIdx.x;  int n = e >> 7, k = e & 127;  wlpt[e] = (__bf16)Wlp[(size_t)k * 128 + n]; }
    else if (wb < 896) { e = (wb - 832) * 256 + threadIdx.x;  int n = e >> 7, k = e & 127;  wrpt[e] = (__bf16)Wrp[(size_t)k * 128 + n]; }
    else if (wb < 960) { e = (wb - 896) * 256 + threadIdx.x;  int n = e >> 7, k = e & 127;  wrgt[e] = (__bf16)Wrg[(size_t)k * 128 + n]; }
    else if (wb < 1024){ e = (wb - 960) * 256 + threadIdx.x;  int n = e >> 7, k = e & 127;  wnlt[e] = (__bf16)Wnl[(size_t)k * 128 + n]; }
    else if (wb < 1088){ e = (wb - 1024) * 256 + threadIdx.x; int n = e >> 7, k = e & 127;  wnrt[e] = (__bf16)Wnr[(size_t)k * 128 + n]; }
    else               { e = (wb - 1088) * 256 + threadIdx.x; int n = e >> 7, k = e & 127;  wfct[e] = (__bf16)(n < 1000 ? Wfc[(size_t)k * 1000 + n] : 0.f); }
}

// =====================================================================
// MFMA bf16 GEMM with global_load_lds staging (round-6 proven structure).
//   ACT: 0 none, 2 row-l2norm (N==128, gridDim.y==1)
//   DUALW: O2 (bf16) = A1@B2 + b2
//   EMIT: 0 -> O1 fp32; 2 -> Ob bf16; 3 -> Oi packed dword {x(lo), hl(hi)}
//   j.af32 (runtime): A1 is fp32; stage via reg loads + cvt + linear ds_write
// =====================================================================
struct GJob {
    const void* A1;
    const __bf16* B1; const __bf16* B2;
    const float* b1; const float* b2;
    float* O1; __bf16* O2; unsigned* Oi; __bf16* Ob;
    int M, N, Kp, ksteps, af32;
};

template<int ACT, int DUALW, int EMIT>
__global__ __launch_bounds__(256) void gemm_bt(GJob j0, GJob j1, int split)
{
    __shared__ __align__(16) __bf16 As[64 * 32];
    __shared__ __align__(16) __bf16 Bs[128 * 32];
    __shared__ __align__(16) __bf16 B2s[DUALW ? 128 * 32 : 8];
    __shared__ float part[2][64];

    GJob j; int bx;
    if ((int)blockIdx.x < split) { j = j0; bx = blockIdx.x; }
    else { j = j1; bx = blockIdx.x - split; }

    const int tid = threadIdx.x;
    const int wave = tid >> 6, lane = tid & 63;
    const int wr = wave >> 1, wc = wave & 1;
    const int l15 = lane & 15, lh = lane >> 4;
    const int row0 = bx * 64;
    const int col0 = blockIdx.y * 128;

    const __bf16* A1b = (const __bf16*)j.A1;
    const float*  A1f = (const float*)j.A1;

    const size_t aoff = (size_t)(row0 + (tid >> 2)) * j.Kp + (tid & 3) * 8;
    const size_t afoff = (size_t)min(row0 + (tid >> 2), j.M - 1) * j.Kp + (tid & 3) * 8;
    const size_t boff0 = (size_t)(col0 + (tid >> 2)) * j.Kp + (tid & 3) * 8;
    const size_t boff1 = boff0 + (size_t)64 * j.Kp;
    char* alds   = (char*)As + wave * 1024;
    char* blds0  = (char*)Bs + wave * 1024;
    char* blds1  = (char*)Bs + 4096 + wave * 1024;
    char* b2lds0 = (char*)B2s + wave * 1024;
    char* b2lds1 = (char*)B2s + 4096 + wave * 1024;

    f32x4 acc[2][4], acc2[2][4];
#pragma unroll
    for (int fm = 0; fm < 2; fm++)
#pragma unroll
        for (int fn = 0; fn < 4; fn++) {
            acc[fm][fn] = (f32x4)0.f;
            if (DUALW) acc2[fm][fn] = (f32x4)0.f;
        }

    for (int ks = 0; ks < j.ksteps; ks++) {
        const int k0 = ks * 32;
        __syncthreads();
        gl2lds16(j.B1 + boff0 + k0, blds0);
        gl2lds16(j.B1 + boff1 + k0, blds1);
        if constexpr (DUALW) {
            gl2lds16(j.B2 + boff0 + k0, b2lds0);
            gl2lds16(j.B2 + boff1 + k0, b2lds1);
        }
        if (j.af32) {
            const float* ap = A1f + afoff + k0;
            f32x4 v0 = *(const f32x4*)ap;
            f32x4 v1 = *(const f32x4*)(ap + 4);
            __bf16 pk[8];
#pragma unroll
            for (int i = 0; i < 4; i++) { pk[i] = (__bf16)v0[i]; pk[4 + i] = (__bf16)v1[i]; }
            *(bf16x8*)&As[(tid >> 2) * 32 + (tid & 3) * 8] = *(bf16x8*)pk;
        } else {
            gl2lds16(A1b + aoff + k0, alds);
        }
        __syncthreads();

#pragma unroll
        for (int fm = 0; fm < 2; fm++) {
            bf16x8 a = *(const bf16x8*)&As[(wr * 32 + fm * 16 + l15) * 32 + lh * 8];
#pragma unroll
            for (int fn = 0; fn < 4; fn++) {
                bf16x8 b = *(const bf16x8*)&Bs[(wc * 64 + fn * 16 + l15) * 32 + lh * 8];
                acc[fm][fn] = __builtin_amdgcn_mfma_f32_16x16x32_bf16(a, b, acc[fm][fn], 0, 0, 0);
                if constexpr (DUALW) {
                    bf16x8 b2 = *(const bf16x8*)&B2s[(wc * 64 + fn * 16 + l15) * 32 + lh * 8];
                    acc2[fm][fn] = __builtin_amdgcn_mfma_f32_16x16x32_bf16(a, b2, acc2[fm][fn], 0, 0, 0);
                }
            }
        }
    }

    float bias[4], bias2[4];
#pragma unroll
    for (int fn = 0; fn < 4; fn++) {
        int col = col0 + wc * 64 + fn * 16 + l15;
        bias[fn] = 0.f; bias2[fn] = 0.f;
        if (col < j.N) {
            bias[fn] = j.b1[col];
            if (DUALW) bias2[fn] = j.b2[col];
        }
    }

    float vv[2][4][4];
#pragma unroll
    for (int fm = 0; fm < 2; fm++)
#pragma unroll
        for (int fn = 0; fn < 4; fn++)
#pragma unroll
            for (int r = 0; r < 4; r++) vv[fm][fn][r] = acc[fm][fn][r] + bias[fn];

    float scale[2][4];
#pragma unroll
    for (int fm = 0; fm < 2; fm++)
#pragma unroll
        for (int r = 0; r < 4; r++) scale[fm][r] = 1.f;

    if constexpr (ACT == 2) {
        float s[2][4];
#pragma unroll
        for (int fm = 0; fm < 2; fm++)
#pragma unroll
            for (int r = 0; r < 4; r++) {
                float v = 0.f;
#pragma unroll
                for (int fn = 0; fn < 4; fn++) v += vv[fm][fn][r] * vv[fm][fn][r];
                v += __shfl_xor(v, 1);
                v += __shfl_xor(v, 2);
                v += __shfl_xor(v, 4);
                v += __shfl_xor(v, 8);
                s[fm][r] = v;
            }
        __syncthreads();
        if (l15 == 0) {
#pragma unroll
            for (int fm = 0; fm < 2; fm++)
#pragma unroll
                for (int r = 0; r < 4; r++)
                    part[wc][wr * 32 + fm * 16 + lh * 4 + r] = s[fm][r];
        }
        __syncthreads();
#pragma unroll
        for (int fm = 0; fm < 2; fm++)
#pragma unroll
            for (int r = 0; r < 4; r++) {
                int rl = wr * 32 + fm * 16 + lh * 4 + r;
                float ss = part[0][rl] + part[1][rl];
                scale[fm][r] = 1.f / fmaxf(sqrtf(ss), 1e-12f);
            }
    }

#pragma unroll
    for (int fm = 0; fm < 2; fm++)
#pragma unroll
        for (int fn = 0; fn < 4; fn++)
#pragma unroll
            for (int r = 0; r < 4; r++) {
                int row = row0 + wr * 32 + fm * 16 + lh * 4 + r;
                int col = col0 + wc * 64 + fn * 16 + l15;
                if (row < j.M && col < j.N) {
                    float v = vv[fm][fn][r] * scale[fm][r];
                    if constexpr (EMIT == 0) j.O1[(size_t)row * j.N + col] = v;
                    if constexpr (EMIT == 2) j.Ob[(size_t)row * j.N + col] = (__bf16)v;
                    if constexpr (EMIT == 3) {
                        unsigned short xv = ((const unsigned short*)j.A1)[(size_t)row * 128 + col];
                        j.Oi[(size_t)row * 128 + col] = (unsigned)xv | ((unsigned)f2bbits(v) << 16);
                    }
                    if constexpr (DUALW)
                        j.O2[(size_t)row * j.N + col] = (__bf16)(acc2[fm][fn][r] + bias2[fn]);
                }
            }
}

// =====================================================================
// Fused ea+wa (proven)
// =====================================================================
__global__ __launch_bounds__(256) void ea_wa_kernel(
    const __bf16* __restrict__ xb, const __bf16* __restrict__ rppb, const __bf16* __restrict__ rgpb,
    const __bf16* __restrict__ wl, const __bf16* __restrict__ wrp, const __bf16* __restrict__ wrg,
    const float* __restrict__ blp, const float* __restrict__ brp, const float* __restrict__ brg,
    const int* __restrict__ indeg_pp, const int* __restrict__ indeg_gp,
    float* __restrict__ wpp, float* __restrict__ wgp)
{
    __shared__ __align__(16) __bf16 A1s[64 * 32], A2s[64 * 32], A3s[64 * 32];
    __shared__ __align__(16) __bf16 B1s[128 * 32], B2s[128 * 32], B3s[128 * 32];

    const int tid = threadIdx.x;
    const int wave = tid >> 6, lane = tid & 63;
    const int wr = wave >> 1, wc = wave & 1;
    const int l15 = lane & 15, lh = lane >> 4;
    const int row0 = blockIdx.x * 64;

    const size_t aoff = (size_t)(row0 + (tid >> 2)) * 128 + (tid & 3) * 8;
    const size_t boff0 = (size_t)(tid >> 2) * 128 + (tid & 3) * 8;
    const size_t boff1 = boff0 + (size_t)64 * 128;
    char* a1 = (char*)A1s + wave * 1024;
    char* a2 = (char*)A2s + wave * 1024;
    char* a3 = (char*)A3s + wave * 1024;
    char* b1l0 = (char*)B1s + wave * 1024, *b1l1 = (char*)B1s + 4096 + wave * 1024;
    char* b2l0 = (char*)B2s + wave * 1024, *b2l1 = (char*)B2s + 4096 + wave * 1024;
    char* b3l0 = (char*)B3s + wave * 1024, *b3l1 = (char*)B3s + 4096 + wave * 1024;

    f32x4 accL[2][4], accP[2][4], accG[2][4];
#pragma unroll
    for (int fm = 0; fm < 2; fm++)
#pragma unroll
        for (int fn = 0; fn < 4; fn++) {
            accL[fm][fn] = (f32x4)0.f; accP[fm][fn] = (f32x4)0.f; accG[fm][fn] = (f32x4)0.f;
        }

    for (int ks = 0; ks < 4; ks++) {
        const int k0 = ks * 32;
        __syncthreads();
        gl2lds16(xb + aoff + k0, a1);
        gl2lds16(rppb + aoff + k0, a2);
        gl2lds16(rgpb + aoff + k0, a3);
        gl2lds16(wl + boff0 + k0, b1l0);  gl2lds16(wl + boff1 + k0, b1l1);
        gl2lds16(wrp + boff0 + k0, b2l0); gl2lds16(wrp + boff1 + k0, b2l1);
        gl2lds16(wrg + boff0 + k0, b3l0); gl2lds16(wrg + boff1 + k0, b3l1);
        __syncthreads();

#pragma unroll
        for (int fm = 0; fm < 2; fm++) {
            const int arow = (wr * 32 + fm * 16 + l15) * 32 + lh * 8;
            bf16x8 aL = *(const bf16x8*)&A1s[arow];
            bf16x8 aP = *(const bf16x8*)&A2s[arow];
            bf16x8 aG = *(const bf16x8*)&A3s[arow];
#pragma unroll
            for (int fn = 0; fn < 4; fn++) {
                const int brow = (wc * 64 + fn * 16 + l15) * 32 + lh * 8;
                bf16x8 bL = *(const bf16x8*)&B1s[brow];
                bf16x8 bP = *(const bf16x8*)&B2s[brow];
                bf16x8 bG = *(const bf16x8*)&B3s[brow];
                accL[fm][fn] = __builtin_amdgcn_mfma_f32_16x16x32_bf16(aL, bL, accL[fm][fn], 0, 0, 0);
                accP[fm][fn] = __builtin_amdgcn_mfma_f32_16x16x32_bf16(aP, bP, accP[fm][fn], 0, 0, 0);
                accG[fm][fn] = __builtin_amdgcn_mfma_f32_16x16x32_bf16(aG, bG, accG[fm][fn], 0, 0, 0);
            }
        }
    }

    float bp[4], bg[4];
#pragma unroll
    for (int fn = 0; fn < 4; fn++) {
        int col = wc * 64 + fn * 16 + l15;
        bp[fn] = blp[col] + brp[col];
        bg[fn] = blp[col] + brg[col];
    }

#pragma unroll
    for (int fm = 0; fm < 2; fm++)
#pragma unroll
        for (int r = 0; r < 4; r++) {
            int row = row0 + wr * 32 + fm * 16 + lh * 4 + r;
            int rr = min(row, NP - 1);
            int npp = indeg_pp[rr], ngp = indeg_gp[rr];
#pragma unroll
            for (int fn = 0; fn < 4; fn++) {
                int col = wc * 64 + fn * 16 + l15;
                float app = accL[fm][fn][r] + accP[fm][fn][r] + bp[fn];
                app = app > 0.f ? app : (__expf(app) - 1.f);
                float agp = accL[fm][fn][r] + accG[fm][fn][r] + bg[fn];
                agp = agp > 0.f ? agp : (__expf(agp) - 1.f);
                float wppv = 0.f, wgpv = 0.f;
                if (npp > 0 && ngp > 0) {
                    float mx = fmaxf(app, agp);
                    float ep = __expf(app - mx), eg = __expf(agp - mx);
                    float den = (float)npp * ep + (float)ngp * eg;
                    wppv = ep / den; wgpv = eg / den;
                } else if (npp > 0) wppv = 1.f / (float)npp;
                else if (ngp > 0) wgpv = 1.f / (float)ngp;
                if (row < NP) {
                    wpp[(size_t)row * DH + col] = wppv;
                    wgp[(size_t)row * DH + col] = wgpv;
                }
            }
        }
}

// ---------------- GCN aggregation: dword gather (2ch/thread), 2-edge-parity groups, unroll-4 ----------------
__global__ __launch_bounds__(128) void rst_agg_kernel(const __bf16* __restrict__ x,
                                                      const int* __restrict__ row_ptr,
                                                      const int2* __restrict__ edata,
                                                      const int* __restrict__ indeg_pp,
                                                      const int* __restrict__ indeg_gp,
                                                      __bf16* __restrict__ rppb, __bf16* __restrict__ rgpb)
{
    const int d = blockIdx.x;  // < NP
    const int tid = threadIdx.x;
    const unsigned c2 = tid & 63;
    const int h = tid >> 6;
    const int beg = row_ptr[d], end = row_ptr[d + 1];
    const unsigned int* xu = (const unsigned int*)x;
    float spp0 = 0.f, spp1 = 0.f, sgp0 = 0.f, sgp1 = 0.f;

    int i = beg + h;
    for (; i + 6 < end; i += 8) {
        int2 e0 = edata[i], e1 = edata[i + 2], e2 = edata[i + 4], e3 = edata[i + 6];
        unsigned u0 = xu[(((unsigned)e0.x & 0xFFFFu) << 6) | c2];
        unsigned u1 = xu[(((unsigned)e1.x & 0xFFFFu) << 6) | c2];
        unsigned u2 = xu[(((unsigned)e2.x & 0xFFFFu) << 6) | c2];
        unsigned u3 = xu[(((unsigned)e3.x & 0xFFFFu) << 6) | c2];
#pragma unroll
        for (int k = 0; k < 4; k++) {
            unsigned u = (k == 0) ? u0 : (k == 1) ? u1 : (k == 2) ? u2 : u3;
            int2 e = (k == 0) ? e0 : (k == 1) ? e1 : (k == 2) ? e2 : e3;
            float lo = __uint_as_float(u << 16);
            float hi = __uint_as_float(u & 0xFFFF0000u);
            float sc = __int_as_float(e.y);
            if ((e.x >> 16) == 0) { spp0 = fmaf(lo, sc, spp0); spp1 = fmaf(hi, sc, spp1); }
            else                  { sgp0 = fmaf(lo, sc, sgp0); sgp1 = fmaf(hi, sc, sgp1); }
        }
    }
    for (; i < end; i += 2) {
        int2 e = edata[i];
        unsigned u = xu[(((unsigned)e.x & 0xFFFFu) << 6) | c2];
        float lo = __uint_as_float(u << 16);
        float hi = __uint_as_float(u & 0xFFFF0000u);
        float sc = __int_as_float(e.y);
        if ((e.x >> 16) == 0) { spp0 = fmaf(lo, sc, spp0); spp1 = fmaf(hi, sc, spp1); }
        else                  { sgp0 = fmaf(lo, sc, sgp0); sgp1 = fmaf(hi, sc, sgp1); }
    }

    __shared__ float red[4][64];
    if (h == 1) { red[0][c2] = spp0; red[1][c2] = spp1; red[2][c2] = sgp0; red[3][c2] = sgp1; }
    __syncthreads();
    if (h == 0) {
        spp0 += red[0][c2]; spp1 += red[1][c2]; sgp0 += red[2][c2]; sgp1 += red[3][c2];
        float ipp = rsqrtf((float)max(indeg_pp[d], 1));
        float igp = rsqrtf((float)max(indeg_gp[d], 1));
        union { unsigned u; __bf16 b[2]; } wp, wg;
        wp.b[0] = (__bf16)(spp0 * ipp); wp.b[1] = (__bf16)(spp1 * ipp);
        wg.b[0] = (__bf16)(sgp0 * igp); wg.b[1] = (__bf16)(sgp1 * igp);
        ((unsigned*)rppb)[((unsigned)d << 6) | c2] = wp.u;
        ((unsigned*)rgpb)[((unsigned)d << 6) | c2] = wg.u;
    }
}

// ---------------- node attention: 2ch/lane uint2 gather, edge-parity waves, unroll-4 ----------------
__global__ __launch_bounds__(128) void node_attn_kernel(const unsigned int* __restrict__ xhl,
                                                        const __bf16* __restrict__ hrb,
                                                        const float* __restrict__ wpp_arr,
                                                        const float* __restrict__ wgp_arr,
                                                        const int* __restrict__ indeg_pg,
                                                        const int* __restrict__ row_ptr,
                                                        const int2* __restrict__ edata,
                                                        __bf16* __restrict__ hb)
{
    const int d = blockIdx.x;
    const int tid = threadIdx.x;
    const unsigned c2 = tid & 63;   // channel pair: 2*c2, 2*c2+1
    const int h = tid >> 6;         // edge parity wave
    const int beg = row_ptr[d], end = row_ptr[d + 1];

    unsigned hru = ((const unsigned*)hrb)[((size_t)d << 6) | c2];
    const float hr0 = __uint_as_float(hru << 16);
    const float hr1 = __uint_as_float(hru & 0xFFFF0000u);
    float wp0, wp1, wg0, wg1;
    if (d < NP) {
        float2 wp = ((const float2*)wpp_arr)[((size_t)d << 6) | c2];
        float2 wg = ((const float2*)wgp_arr)[((size_t)d << 6) | c2];
        wp0 = wp.x; wp1 = wp.y; wg0 = wg.x; wg1 = wg.y;
    } else {
        float w = 1.f / (float)max(indeg_pg[d - NP], 1);
        wp0 = wp1 = wg0 = wg1 = w;
    }
    float ssum0 = 0.f, ssum1 = 0.f, acc0 = 0.f, acc1 = 0.f;
    const uint2* xp = (const uint2*)xhl;   // uint2 = 2 channels of packed {x, hl}

    auto body = [&](int p, uint2 u) {
        bool pp = (p >> 16) == 0;
        float a0 = pp ? wp0 : wg0;
        float a1 = pp ? wp1 : wg1;
        float x0  = __uint_as_float(u.x << 16);
        float hl0 = __uint_as_float(u.x & 0xFFFF0000u);
        float x1  = __uint_as_float(u.y << 16);
        float hl1 = __uint_as_float(u.y & 0xFFFF0000u);
        float e0 = (hl0 + hr0) * a0; e0 = fmaxf(e0, -0.2f * e0);
        float e1 = (hl1 + hr1) * a1; e1 = fmaxf(e1, -0.2f * e1);
        float p0 = __expf(e0), p1 = __expf(e1);
        ssum0 += p0; ssum1 += p1;
        acc0 = fmaf(p0, x0, acc0);
        acc1 = fmaf(p1, x1, acc1);
    };

    int i = beg + h;
    for (; i + 6 < end; i += 8) {   // 4 edges per wave per iter (stride 2)
        int p0 = edata[i].x, p1 = edata[i + 2].x, p2 = edata[i + 4].x, p3 = edata[i + 6].x;
        uint2 u0 = xp[(((unsigned)p0 & 0xFFFFu) << 6) | c2];
        uint2 u1 = xp[(((unsigned)p1 & 0xFFFFu) << 6) | c2];
        uint2 u2 = xp[(((unsigned)p2 & 0xFFFFu) << 6) | c2];
        uint2 u3 = xp[(((unsigned)p3 & 0xFFFFu) << 6) | c2];
        body(p0, u0); body(p1, u1); body(p2, u2); body(p3, u3);
    }
    for (; i < end; i += 2) {
        int p = edata[i].x;
        uint2 u = xp[(((unsigned)p & 0xFFFFu) << 6) | c2];
        body(p, u);
    }

    __shared__ float red[4][64];
    if (h == 1) { red[0][c2] = ssum0; red[1][c2] = ssum1; red[2][c2] = acc0; red[3][c2] = acc1; }
    __syncthreads();
    if (h == 0) {
        ssum0 += red[0][c2]; ssum1 += red[1][c2];
        acc0 += red[2][c2];  acc1 += red[3][c2];
        float o0 = (end > beg) ? acc0 / ssum0 : 0.f;
        float o1 = (end > beg) ? acc1 / ssum1 : 0.f;
        union { unsigned u; __bf16 b[2]; } o;
        o.b[0] = (__bf16)o0; o.b[1] = (__bf16)o1;
        ((unsigned*)hb)[((size_t)d << 6) | c2] = o.u;
    }
}

extern "C" void kernel_launch(void* const* d_in, const int* in_sizes, int n_in,
                              void* d_out, int out_size, void* d_ws, size_t ws_size,
                              hipStream_t stream)
{
    const float* x_protein = (const float*)d_in[0];
    const float* x_go      = (const float*)d_in[1];
    const int* src_pp = (const int*)d_in[2];
    const int* dst_pp = (const int*)d_in[3];
    const int* src_pg = (const int*)d_in[4];
    const int* dst_pg = (const int*)d_in[5];
    const int* src_gp = (const int*)d_in[6];
    const int* dst_gp = (const int*)d_in[7];
    const float* W1p = (const float*)d_in[8];
    const float* b1p = (const float*)d_in[9];
    const float* W1g = (const float*)d_in[10];
    const float* b1g = (const float*)d_in[11];
    const float* Wl_p = (const float*)d_in[12];
    const float* bl_p = (const float*)d_in[13];
    // Wl_g (14), bl_g (15) dead: go-dst type-alpha is uniform 1/n
    const float* Wr_p = (const float*)d_in[16];
    const float* br_p = (const float*)d_in[17];
    const float* Wr_g = (const float*)d_in[18];
    const float* br_g = (const float*)d_in[19];
    const float* Wnl = (const float*)d_in[20];
    const float* bnl = (const float*)d_in[21];
    const float* Wnr = (const float*)d_in[22];
    const float* bnr = (const float*)d_in[23];
    const float* Wfc = (const float*)d_in[24];
    const float* bfc = (const float*)d_in[25];
    float* out = (float*)d_out;

    // ---- workspace layout (4B words); total ~63 MB ----
    size_t off = 0;
    char* base = (char*)d_ws;
    auto alloc = [&](size_t words) { void* p = base + off * 4; off += (words + 7) & ~(size_t)7; return p; };

    __bf16* xb  = (__bf16*)alloc((size_t)25024 * 128 / 2);
    __bf16* hrb = (__bf16*)alloc((size_t)25024 * 128 / 2);
    // U region: rppb+rgpb until ea_wa; xhl after (hlr writes it)
    char* U = (char*)alloc((size_t)25024 * 128);
    __bf16* rppb = (__bf16*)U;
    __bf16* rgpb = (__bf16*)(U + (size_t)20032 * 128 * 2);
    unsigned int* xhl = (unsigned int*)U;
    // R1: hist partials -> xgb -> (wpp, wgp, haggb)
    char* R1 = (char*)alloc((size_t)5128192 + 2588672);
    int*    partial = (int*)R1;
    __bf16* xgb = (__bf16*)R1;
    float*  wpp = (float*)R1;
    float*  wgp = wpp + (size_t)20000 * 128;
    __bf16* haggb = (__bf16*)(wgp + (size_t)20000 * 128);
    __bf16* w1pt = (__bf16*)alloc(128 * 512 / 2);
    __bf16* w1gt = (__bf16*)alloc(128 * 1024 / 2);
    __bf16* wlpt = (__bf16*)alloc(128 * 128 / 2);
    __bf16* wrpt = (__bf16*)alloc(128 * 128 / 2);
    __bf16* wrgt = (__bf16*)alloc(128 * 128 / 2);
    __bf16* wnlt = (__bf16*)alloc(128 * 128 / 2);
    __bf16* wnrt = (__bf16*)alloc(128 * 128 / 2);
    __bf16* wfct = (__bf16*)alloc(1024 * 128 / 2);
    int* outdeg_pp = (int*)alloc(NP);
    int* outdeg_pg = (int*)alloc(NP);
    int* outdeg_gp = (int*)alloc(NG);
    int* indeg_pp  = (int*)alloc(NP);
    int* indeg_gp  = (int*)alloc(NP);
    int* indeg_pg  = (int*)alloc(NG);
    int* fill      = (int*)alloc((size_t)NTOT * FS);
    int* row_ptr   = (int*)alloc(NTOT + 1);
    int2* edata    = (int2*)alloc((size_t)ETOT * 2);

    // 1) degree histograms (partial, LDS-private)
    hist_part_kernel<<<dim3(HB, 6), 1024, 0, stream>>>(
        src_pp, dst_pp, src_pg, dst_pg, src_gp, dst_gp, partial);
    // 2) merge partials + zero fill counters (job 6)
    hist_merge_kernel<<<dim3((NTOT * FS + 255) / 256, 7), 256, 0, stream>>>(
        partial, outdeg_pp, indeg_pp, outdeg_pg, indeg_pg, outdeg_gp, indeg_gp, fill);
    // 3) row_ptr scan
    scan_kernel<<<1, 1024, 0, stream>>>(indeg_pp, indeg_gp, indeg_pg, row_ptr);
    // 4) CSR scatter
    scatter_kernel<<<(ETOT + 255) / 256, 256, 0, stream>>>(
        src_pp, dst_pp, src_pg, dst_pg, src_gp, dst_gp,
        outdeg_pp, outdeg_pg, outdeg_gp, row_ptr, fill, edata);
    // 5) conversions: x_go + all weights (x_protein handled in-GEMM via af32)
    conv_all_kernel<<<4128, 256, 0, stream>>>(
        x_go, W1p, W1g, Wl_p, Wr_p, Wr_g, Wnl, Wnr, Wfc,
        xgb, w1pt, w1gt, wlpt, wrpt, wrgt, wnlt, wnrt, wfct);

    // 6) fused projections + l2norm -> xb (bf16); protein A = fp32 direct
    {
        GJob p0 = { x_protein, w1pt, nullptr, b1p, nullptr, nullptr, nullptr, nullptr, xb,
                    NP, 128, 512, 16, 1 };
        GJob p1 = { xgb, w1gt, nullptr, b1g, nullptr, nullptr, nullptr, nullptr,
                    xb + (size_t)NP * 128, NG, 128, 1024, 32, 0 };
        gemm_bt<2, 0, 2><<<392, 256, 0, stream>>>(p0, p1, 313);
    }

    // 7) GCN aggregation for type attention (protein dst only) — dword gather
    rst_agg_kernel<<<NP, 128, 0, stream>>>(xb, row_ptr, edata, indeg_pp, indeg_gp, rppb, rgpb);

    // 8) fused ea + type-softmax weights -> wpp/wgp (fp32); rppb/rgpb dead after this
    ea_wa_kernel<<<313, 256, 0, stream>>>(xb, rppb, rgpb, wlpt, wrpt, wrgt,
                                          bl_p, br_p, br_g, indeg_pp, indeg_gp, wpp, wgp);

    // 9) node attention projections: packed xhl {x, hl} + hr (bf16 dense)
    {
        GJob h0 = { xb, wnlt, wnrt, bnl, bnr, nullptr, hrb, xhl, nullptr,
                    NTOT, 128, 128, 4, 0 };
        gemm_bt<0, 1, 3><<<391, 256, 0, stream>>>(h0, h0, 1 << 30);
    }

    // 10) node attention + aggregation -> haggb
    node_attn_kernel<<<NTOT, 128, 0, stream>>>(xhl, hrb, wpp, wgp, indeg_pg, row_ptr, edata, haggb);

    // 11) final classifier: out = hagg@Wfc + bfc
    {
        GJob o0 = { haggb, wfct, nullptr, bfc, nullptr, out, nullptr, nullptr, nullptr,
                    NTOT, NCLS, 128, 4, 0 };
        gemm_bt<0, 0, 0><<<dim3(391, 8), 256, 0, stream>>>(o0, o0, 1 << 30);
    }

    (void)in_sizes; (void)n_in; (void)out_size; (void)ws_size;
}

// Round 13
// 245.329 us; speedup vs baseline: 1.0107x; 1.0107x over previous
//
#include <hip/hip_runtime.h>
#include <math.h>

#define NP 20000
#define NG 5000
#define NTOT 25000
#define DF 512
#define NCLS 1000
#define DH 128
#define EPP 240000
#define EPG 100000
#define EGP 100000
#define ETOT 440000
#define FS 16   // fill stride (one counter per 64B line)
#define HB 16   // partial-histogram blocks per job
#define SCB 1719  // scatter blocks = ceil(ETOT/256)

typedef __attribute__((ext_vector_type(8))) __bf16 bf16x8;
typedef __attribute__((ext_vector_type(4))) float f32x4;

__device__ __forceinline__ void gl2lds16(const void* g, void* l) {
    __builtin_amdgcn_global_load_lds(
        (const __attribute__((address_space(1))) unsigned int*)g,
        (__attribute__((address_space(3))) unsigned int*)l, 16, 0, 0);
}

__device__ __forceinline__ float b2f(unsigned short u) {
    union { unsigned int i; float f; } c; c.i = ((unsigned int)u) << 16; return c.f;
}

__device__ __forceinline__ unsigned short f2bbits(float v) {
    __bf16 t = (__bf16)v;
    return __builtin_bit_cast(unsigned short, t);
}

// ---------------- partial histograms: HB blocks/job, LDS-private, plain stores ----------------
__global__ __launch_bounds__(1024) void hist_part_kernel(
    const int* __restrict__ src_pp, const int* __restrict__ dst_pp,
    const int* __restrict__ src_pg, const int* __restrict__ dst_pg,
    const int* __restrict__ src_gp, const int* __restrict__ dst_gp,
    int* __restrict__ partial)
{
    __shared__ int bins[20000];
    const int job = blockIdx.y, b = blockIdx.x;
    const int* idx; int nbins, nedge; size_t pbase;
    switch (job) {
    case 0: idx = src_pp; nbins = 20000; nedge = EPP; pbase = 0;       break;
    case 1: idx = dst_pp; nbins = 20000; nedge = EPP; pbase = 320000;  break;
    case 2: idx = src_pg; nbins = 20000; nedge = EPG; pbase = 640000;  break;
    case 3: idx = dst_pg; nbins = 5000;  nedge = EPG; pbase = 960000;  break;
    case 4: idx = src_gp; nbins = 5000;  nedge = EGP; pbase = 1040000; break;
    default: idx = dst_gp; nbins = 20000; nedge = EGP; pbase = 1120000; break;
    }
    for (int i = threadIdx.x; i < nbins; i += 1024) bins[i] = 0;
    __syncthreads();
    const int chunk = (nedge + HB - 1) / HB;
    const int e0 = b * chunk, e1 = min(e0 + chunk, nedge);
    for (int e = e0 + threadIdx.x; e < e1; e += 1024) atomicAdd(&bins[idx[e]], 1);
    __syncthreads();
    int* dst = partial + pbase + (size_t)b * nbins;
    for (int i = threadIdx.x; i < nbins; i += 1024) dst[i] = bins[i];
}

// ---------------- merge partials -> degree arrays; job 6 zeroes the fill counters ----------------
__global__ __launch_bounds__(256) void hist_merge_kernel(const int* __restrict__ partial,
    int* __restrict__ outdeg_pp, int* __restrict__ indeg_pp,
    int* __restrict__ outdeg_pg, int* __restrict__ indeg_pg,
    int* __restrict__ outdeg_gp, int* __restrict__ indeg_gp,
    int* __restrict__ fill)
{
    const int job = blockIdx.y;
    const int bin = blockIdx.x * 256 + threadIdx.x;
    if (job == 6) {
        if (bin < NTOT * FS) fill[bin] = 0;
        return;
    }
    const int nbins = (job == 3 || job == 4) ? 5000 : 20000;
    if (bin >= nbins) return;
    size_t pbase; int* outp;
    switch (job) {
    case 0: pbase = 0;       outp = outdeg_pp; break;
    case 1: pbase = 320000;  outp = indeg_pp;  break;
    case 2: pbase = 640000;  outp = outdeg_pg; break;
    case 3: pbase = 960000;  outp = indeg_pg;  break;
    case 4: pbase = 1040000; outp = outdeg_gp; break;
    default: pbase = 1120000; outp = indeg_gp; break;
    }
    const int* p = partial + pbase + bin;
    int s = 0;
#pragma unroll
    for (int b = 0; b < HB; b++) s += p[(size_t)b * nbins];
    outp[bin] = s;
}

// ---------------- exclusive scan -> row_ptr[NTOT+1] ----------------
__global__ __launch_bounds__(1024) void scan_kernel(const int* __restrict__ indeg_pp,
                                                    const int* __restrict__ indeg_gp,
                                                    const int* __restrict__ indeg_pg,
                                                    int* __restrict__ row_ptr)
{
    __shared__ int part[1024];
    int t = threadIdx.x;
    const int CH = (NTOT + 1023) / 1024;
    int base = t * CH;
    auto cntf = [&](int idx) -> int {
        return (idx < NP) ? (indeg_pp[idx] + indeg_gp[idx]) : indeg_pg[idx - NP];
    };
    int s = 0;
    for (int i = 0; i < CH; i++) { int idx = base + i; if (idx < NTOT) s += cntf(idx); }
    part[t] = s;
    __syncthreads();
    for (int off = 1; off < 1024; off <<= 1) {
        int v = (t >= off) ? part[t - off] : 0;
        __syncthreads();
        part[t] += v;
        __syncthreads();
    }
    int run = (t == 0) ? 0 : part[t - 1];
    for (int i = 0; i < CH; i++) {
        int idx = base + i;
        if (idx < NTOT) { row_ptr[idx] = run; run += cntf(idx); }
    }
    if (t == 1023) row_ptr[NTOT] = part[1023];
}

// =====================================================================
// Fused scatter + conversions (ranged 1D grid, no LDS, low VGPR):
//  blocks [0,SCB): CSR scatter (atomic/latency bound)
//  blocks [SCB,SCB+2528): x_go -> bf16 (stream bound)
//  blocks [SCB+2528,SCB+4128): weight transposes
// Overlaps the atomic-latency scatter with streaming conversions.
// =====================================================================
__global__ __launch_bounds__(256) void scatter_conv_kernel(
    const int* __restrict__ src_pp, const int* __restrict__ dst_pp,
    const int* __restrict__ src_pg, const int* __restrict__ dst_pg,
    const int* __restrict__ src_gp, const int* __restrict__ dst_gp,
    const int* __restrict__ outdeg_pp, const int* __restrict__ outdeg_pg,
    const int* __restrict__ outdeg_gp,
    const int* __restrict__ row_ptr, int* fill, int2* __restrict__ edata,
    const float* __restrict__ xg,
    const float* W1p, const float* W1g, const float* Wlp, const float* Wrp, const float* Wrg,
    const float* Wnl, const float* Wnr, const float* Wfc,
    __bf16* __restrict__ xgb,
    __bf16* w1pt, __bf16* w1gt, __bf16* wlpt, __bf16* wrpt, __bf16* wrgt,
    __bf16* wnlt, __bf16* wnrt, __bf16* wfct)
{
    const int blk = blockIdx.x;
    if (blk < SCB) {
        int e = blk * 256 + threadIdx.x;
        int s, d, t; float sc;
        if (e < EPP) {
            s = src_pp[e]; d = dst_pp[e]; t = 0;
            sc = rsqrtf((float)max(outdeg_pp[s], 1));
        } else if (e < EPP + EPG) {
            int i = e - EPP; s = src_pg[i]; d = NP + dst_pg[i]; t = 1;
            sc = rsqrtf((float)max(outdeg_pg[s], 1));
        } else if (e < ETOT) {
            int i = e - EPP - EPG; int sl = src_gp[i]; s = NP + sl; d = dst_gp[i]; t = 2;
            sc = rsqrtf((float)max(outdeg_gp[sl], 1));
        } else return;
        int pos = row_ptr[d] + atomicAdd(&fill[d * FS], 1);
        edata[pos] = make_int2(s | (t << 16), __float_as_int(sc));
        return;
    }
    const int b = blk - SCB;
    if (b < 2528) {
        long long e = ((long long)b * 256 + threadIdx.x) * 8;
        int row = (int)(e >> 10), k = (int)(e & 1023);
        __bf16 pk[8];
        if (row < NG && k + 7 < 1000) {
            f32x4 v0 = *(const f32x4*)(xg + (size_t)row * 1000 + k);
            f32x4 v1 = *(const f32x4*)(xg + (size_t)row * 1000 + k + 4);
#pragma unroll
            for (int i = 0; i < 4; i++) { pk[i] = (__bf16)v0[i]; pk[4 + i] = (__bf16)v1[i]; }
        } else {
#pragma unroll
            for (int i = 0; i < 8; i++) {
                int kk = k + i;
                pk[i] = (__bf16)((row < NG && kk < 1000) ? xg[(size_t)row * 1000 + kk] : 0.f);
            }
        }
        *(bf16x8*)(xgb + e) = *(bf16x8*)pk;
        return;
    }
    int wb = b - 2528;
    int e;
    if (wb < 256)      { e = wb * 256 + threadIdx.x;          int n = e >> 9, k = e & 511;  w1pt[e] = (__bf16)W1p[(size_t)k * 128 + n]; }
    else if (wb < 768) { e = (wb - 256) * 256 + threadIdx.x;  int n = e >> 10, k = e & 1023; w1gt[e] = (__bf16)(k < 1000 ? W1g[(size_t)k * 128 + n] : 0.f); }
    else if (wb < 832) { e = (wb - 768) * 256 + threadIdx.x;  int n = e >> 7, k = e & 127;  wlpt[e] = (__bf16)Wlp[(size_t)k * 128 + n]; }
    else if (wb < 896) { e = (wb - 832) * 256 + threadIdx.x;  int n = e >> 7, k = e & 127;  wrpt[e] = (__bf16)Wrp[(size_t)k * 128 + n]; }
    else if (wb < 960) { e = (wb - 896) * 256 + threadIdx.x;  int n = e >> 7, k = e & 127;  wrgt[e] = (__bf16)Wrg[(size_t)k * 128 + n]; }
    else if (wb < 1024){ e = (wb - 960) * 256 + threadIdx.x;  int n = e >> 7, k = e & 127;  wnlt[e] = (__bf16)Wnl[(size_t)k * 128 + n]; }
    else if (wb < 1088){ e = (wb - 1024) * 256 + threadIdx.x; int n = e >> 7, k = e & 127;  wnrt[e] = (__bf16)Wnr[(size_t)k * 128 + n]; }
    else               { e = (wb - 1088) * 256 + threadIdx.x; int n = e >> 7, k = e & 127;  wfct[e] = (__bf16)(n < 1000 ? Wfc[(size_t)k * 1000 + n] : 0.f); }
}

// =====================================================================
// MFMA bf16 GEMM with global_load_lds staging (round-6 proven structure).
//   ACT: 0 none, 2 row-l2norm (N==128, gridDim.y==1)
//   DUALW: O2 (bf16) = A1@B2 + b2
//   EMIT: 0 -> O1 fp32; 2 -> Ob bf16; 3 -> Oi packed dword {x(lo), hl(hi)}
//   j.af32 (runtime): A1 is fp32; stage via reg loads + cvt + linear ds_write
// =====================================================================
struct GJob {
    const void* A1;
    const __bf16* B1; const __bf16* B2;
    const float* b1; const float* b2;
    float* O1; __bf16* O2; unsigned* Oi; __bf16* Ob;
    int M, N, Kp, ksteps, af32;
};

template<int ACT, int DUALW, int EMIT>
__global__ __launch_bounds__(256) void gemm_bt(GJob j0, GJob j1, int split)
{
    __shared__ __align__(16) __bf16 As[64 * 32];
    __shared__ __align__(16) __bf16 Bs[128 * 32];
    __shared__ __align__(16) __bf16 B2s[DUALW ? 128 * 32 : 8];
    __shared__ float part[2][64];

    GJob j; int bx;
    if ((int)blockIdx.x < split) { j = j0; bx = blockIdx.x; }
    else { j = j1; bx = blockIdx.x - split; }

    const int tid = threadIdx.x;
    const int wave = tid >> 6, lane = tid & 63;
    const int wr = wave >> 1, wc = wave & 1;
    const int l15 = lane & 15, lh = lane >> 4;
    const int row0 = bx * 64;
    const int col0 = blockIdx.y * 128;

    const __bf16* A1b = (const __bf16*)j.A1;
    const float*  A1f = (const float*)j.A1;

    const size_t aoff = (size_t)(row0 + (tid >> 2)) * j.Kp + (tid & 3) * 8;
    const size_t afoff = (size_t)min(row0 + (tid >> 2), j.M - 1) * j.Kp + (tid & 3) * 8;
    const size_t boff0 = (size_t)(col0 + (tid >> 2)) * j.Kp + (tid & 3) * 8;
    const size_t boff1 = boff0 + (size_t)64 * j.Kp;
    char* alds   = (char*)As + wave * 1024;
    char* blds0  = (char*)Bs + wave * 1024;
    char* blds1  = (char*)Bs + 4096 + wave * 1024;
    char* b2lds0 = (char*)B2s + wave * 1024;
    char* b2lds1 = (char*)B2s + 4096 + wave * 1024;

    f32x4 acc[2][4], acc2[2][4];
#pragma unroll
    for (int fm = 0; fm < 2; fm++)
#pragma unroll
        for (int fn = 0; fn < 4; fn++) {
            acc[fm][fn] = (f32x4)0.f;
            if (DUALW) acc2[fm][fn] = (f32x4)0.f;
        }

    for (int ks = 0; ks < j.ksteps; ks++) {
        const int k0 = ks * 32;
        __syncthreads();
        gl2lds16(j.B1 + boff0 + k0, blds0);
        gl2lds16(j.B1 + boff1 + k0, blds1);
        if constexpr (DUALW) {
            gl2lds16(j.B2 + boff0 + k0, b2lds0);
            gl2lds16(j.B2 + boff1 + k0, b2lds1);
        }
        if (j.af32) {
            const float* ap = A1f + afoff + k0;
            f32x4 v0 = *(const f32x4*)ap;
            f32x4 v1 = *(const f32x4*)(ap + 4);
            __bf16 pk[8];
#pragma unroll
            for (int i = 0; i < 4; i++) { pk[i] = (__bf16)v0[i]; pk[4 + i] = (__bf16)v1[i]; }
            *(bf16x8*)&As[(tid >> 2) * 32 + (tid & 3) * 8] = *(bf16x8*)pk;
        } else {
            gl2lds16(A1b + aoff + k0, alds);
        }
        __syncthreads();

#pragma unroll
        for (int fm = 0; fm < 2; fm++) {
            bf16x8 a = *(const bf16x8*)&As[(wr * 32 + fm * 16 + l15) * 32 + lh * 8];
#pragma unroll
            for (int fn = 0; fn < 4; fn++) {
                bf16x8 b = *(const bf16x8*)&Bs[(wc * 64 + fn * 16 + l15) * 32 + lh * 8];
                acc[fm][fn] = __builtin_amdgcn_mfma_f32_16x16x32_bf16(a, b, acc[fm][fn], 0, 0, 0);
                if constexpr (DUALW) {
                    bf16x8 b2 = *(const bf16x8*)&B2s[(wc * 64 + fn * 16 + l15) * 32 + lh * 8];
                    acc2[fm][fn] = __builtin_amdgcn_mfma_f32_16x16x32_bf16(a, b2, acc2[fm][fn], 0, 0, 0);
                }
            }
        }
    }

    float bias[4], bias2[4];
#pragma unroll
    for (int fn = 0; fn < 4; fn++) {
        int col = col0 + wc * 64 + fn * 16 + l15;
        bias[fn] = 0.f; bias2[fn] = 0.f;
        if (col < j.N) {
            bias[fn] = j.b1[col];
            if (DUALW) bias2[fn] = j.b2[col];
        }
    }

    float vv[2][4][4];
#pragma unroll
    for (int fm = 0; fm < 2; fm++)
#pragma unroll
        for (int fn = 0; fn < 4; fn++)
#pragma unroll
            for (int r = 0; r < 4; r++) vv[fm][fn][r] = acc[fm][fn][r] + bias[fn];

    float scale[2][4];
#pragma unroll
    for (int fm = 0; fm < 2; fm++)
#pragma unroll
        for (int r = 0; r < 4; r++) scale[fm][r] = 1.f;

    if constexpr (ACT == 2) {
        float s[2][4];
#pragma unroll
        for (int fm = 0; fm < 2; fm++)
#pragma unroll
            for (int r = 0; r < 4; r++) {
                float v = 0.f;
#pragma unroll
                for (int fn = 0; fn < 4; fn++) v += vv[fm][fn][r] * vv[fm][fn][r];
                v += __shfl_xor(v, 1);
                v += __shfl_xor(v, 2);
                v += __shfl_xor(v, 4);
                v += __shfl_xor(v, 8);
                s[fm][r] = v;
            }
        __syncthreads();
        if (l15 == 0) {
#pragma unroll
            for (int fm = 0; fm < 2; fm++)
#pragma unroll
                for (int r = 0; r < 4; r++)
                    part[wc][wr * 32 + fm * 16 + lh * 4 + r] = s[fm][r];
        }
        __syncthreads();
#pragma unroll
        for (int fm = 0; fm < 2; fm++)
#pragma unroll
            for (int r = 0; r < 4; r++) {
                int rl = wr * 32 + fm * 16 + lh * 4 + r;
                float ss = part[0][rl] + part[1][rl];
                scale[fm][r] = 1.f / fmaxf(sqrtf(ss), 1e-12f);
            }
    }

#pragma unroll
    for (int fm = 0; fm < 2; fm++)
#pragma unroll
        for (int fn = 0; fn < 4; fn++)
#pragma unroll
            for (int r = 0; r < 4; r++) {
                int row = row0 + wr * 32 + fm * 16 + lh * 4 + r;
                int col = col0 + wc * 64 + fn * 16 + l15;
                if (row < j.M && col < j.N) {
                    float v = vv[fm][fn][r] * scale[fm][r];
                    if constexpr (EMIT == 0) j.O1[(size_t)row * j.N + col] = v;
                    if constexpr (EMIT == 2) j.Ob[(size_t)row * j.N + col] = (__bf16)v;
                    if constexpr (EMIT == 3) {
                        unsigned short xv = ((const unsigned short*)j.A1)[(size_t)row * 128 + col];
                        j.Oi[(size_t)row * 128 + col] = (unsigned)xv | ((unsigned)f2bbits(v) << 16);
                    }
                    if constexpr (DUALW)
                        j.O2[(size_t)row * j.N + col] = (__bf16)(acc2[fm][fn][r] + bias2[fn]);
                }
            }
}

// =====================================================================
// Fused ea+wa (proven)
// =====================================================================
__global__ __launch_bounds__(256) void ea_wa_kernel(
    const __bf16* __restrict__ xb, const __bf16* __restrict__ rppb, const __bf16* __restrict__ rgpb,
    const __bf16* __restrict__ wl, const __bf16* __restrict__ wrp, const __bf16* __restrict__ wrg,
    const float* __restrict__ blp, const float* __restrict__ brp, const float* __restrict__ brg,
    const int* __restrict__ indeg_pp, const int* __restrict__ indeg_gp,
    float* __restrict__ wpp, float* __restrict__ wgp)
{
    __shared__ __align__(16) __bf16 A1s[64 * 32], A2s[64 * 32], A3s[64 * 32];
    __shared__ __align__(16) __bf16 B1s[128 * 32], B2s[128 * 32], B3s[128 * 32];

    const int tid = threadIdx.x;
    const int wave = tid >> 6, lane = tid & 63;
    const int wr = wave >> 1, wc = wave & 1;
    const int l15 = lane & 15, lh = lane >> 4;
    const int row0 = blockIdx.x * 64;

    const size_t aoff = (size_t)(row0 + (tid >> 2)) * 128 + (tid & 3) * 8;
    const size_t boff0 = (size_t)(tid >> 2) * 128 + (tid & 3) * 8;
    const size_t boff1 = boff0 + (size_t)64 * 128;
    char* a1 = (char*)A1s + wave * 1024;
    char* a2 = (char*)A2s + wave * 1024;
    char* a3 = (char*)A3s + wave * 1024;
    char* b1l0 = (char*)B1s + wave * 1024, *b1l1 = (char*)B1s + 4096 + wave * 1024;
    char* b2l0 = (char*)B2s + wave * 1024, *b2l1 = (char*)B2s + 4096 + wave * 1024;
    char* b3l0 = (char*)B3s + wave * 1024, *b3l1 = (char*)B3s + 4096 + wave * 1024;

    f32x4 accL[2][4], accP[2][4], accG[2][4];
#pragma unroll
    for (int fm = 0; fm < 2; fm++)
#pragma unroll
        for (int fn = 0; fn < 4; fn++) {
            accL[fm][fn] = (f32x4)0.f; accP[fm][fn] = (f32x4)0.f; accG[fm][fn] = (f32x4)0.f;
        }

    for (int ks = 0; ks < 4; ks++) {
        const int k0 = ks * 32;
        __syncthreads();
        gl2lds16(xb + aoff + k0, a1);
        gl2lds16(rppb + aoff + k0, a2);
        gl2lds16(rgpb + aoff + k0, a3);
        gl2lds16(wl + boff0 + k0, b1l0);  gl2lds16(wl + boff1 + k0, b1l1);
        gl2lds16(wrp + boff0 + k0, b2l0); gl2lds16(wrp + boff1 + k0, b2l1);
        gl2lds16(wrg + boff0 + k0, b3l0); gl2lds16(wrg + boff1 + k0, b3l1);
        __syncthreads();

#pragma unroll
        for (int fm = 0; fm < 2; fm++) {
            const int arow = (wr * 32 + fm * 16 + l15) * 32 + lh * 8;
            bf16x8 aL = *(const bf16x8*)&A1s[arow];
            bf16x8 aP = *(const bf16x8*)&A2s[arow];
            bf16x8 aG = *(const bf16x8*)&A3s[arow];
#pragma unroll
            for (int fn = 0; fn < 4; fn++) {
                const int brow = (wc * 64 + fn * 16 + l15) * 32 + lh * 8;
                bf16x8 bL = *(const bf16x8*)&B1s[brow];
                bf16x8 bP = *(const bf16x8*)&B2s[brow];
                bf16x8 bG = *(const bf16x8*)&B3s[brow];
                accL[fm][fn] = __builtin_amdgcn_mfma_f32_16x16x32_bf16(aL, bL, accL[fm][fn], 0, 0, 0);
                accP[fm][fn] = __builtin_amdgcn_mfma_f32_16x16x32_bf16(aP, bP, accP[fm][fn], 0, 0, 0);
                accG[fm][fn] = __builtin_amdgcn_mfma_f32_16x16x32_bf16(aG, bG, accG[fm][fn], 0, 0, 0);
            }
        }
    }

    float bp[4], bg[4];
#pragma unroll
    for (int fn = 0; fn < 4; fn++) {
        int col = wc * 64 + fn * 16 + l15;
        bp[fn] = blp[col] + brp[col];
        bg[fn] = blp[col] + brg[col];
    }

#pragma unroll
    for (int fm = 0; fm < 2; fm++)
#pragma unroll
        for (int r = 0; r < 4; r++) {
            int row = row0 + wr * 32 + fm * 16 + lh * 4 + r;
            int rr = min(row, NP - 1);
            int npp = indeg_pp[rr], ngp = indeg_gp[rr];
#pragma unroll
            for (int fn = 0; fn < 4; fn++) {
                int col = wc * 64 + fn * 16 + l15;
                float app = accL[fm][fn][r] + accP[fm][fn][r] + bp[fn];
                app = app > 0.f ? app : (__expf(app) - 1.f);
                float agp = accL[fm][fn][r] + accG[fm][fn][r] + bg[fn];
                agp = agp > 0.f ? agp : (__expf(agp) - 1.f);
                float wppv = 0.f, wgpv = 0.f;
                if (npp > 0 && ngp > 0) {
                    float mx = fmaxf(app, agp);
                    float ep = __expf(app - mx), eg = __expf(agp - mx);
                    float den = (float)npp * ep + (float)ngp * eg;
                    wppv = ep / den; wgpv = eg / den;
                } else if (npp > 0) wppv = 1.f / (float)npp;
                else if (ngp > 0) wgpv = 1.f / (float)ngp;
                if (row < NP) {
                    wpp[(size_t)row * DH + col] = wppv;
                    wgp[(size_t)row * DH + col] = wgpv;
                }
            }
        }
}

// ---------------- GCN aggregation: dword gather (2ch/thread), 2-edge-parity groups, unroll-4 ----------------
__global__ __launch_bounds__(128) void rst_agg_kernel(const __bf16* __restrict__ x,
                                                      const int* __restrict__ row_ptr,
                                                      const int2* __restrict__ edata,
                                                      const int* __restrict__ indeg_pp,
                                                      const int* __restrict__ indeg_gp,
                                                      __bf16* __restrict__ rppb, __bf16* __restrict__ rgpb)
{
    const int d = blockIdx.x;  // < NP
    const int tid = threadIdx.x;
    const unsigned c2 = tid & 63;
    const int h = tid >> 6;
    const int beg = row_ptr[d], end = row_ptr[d + 1];
    const unsigned int* xu = (const unsigned int*)x;
    float spp0 = 0.f, spp1 = 0.f, sgp0 = 0.f, sgp1 = 0.f;

    int i = beg + h;
    for (; i + 6 < end; i += 8) {
        int2 e0 = edata[i], e1 = edata[i + 2], e2 = edata[i + 4], e3 = edata[i + 6];
        unsigned u0 = xu[(((unsigned)e0.x & 0xFFFFu) << 6) | c2];
        unsigned u1 = xu[(((unsigned)e1.x & 0xFFFFu) << 6) | c2];
        unsigned u2 = xu[(((unsigned)e2.x & 0xFFFFu) << 6) | c2];
        unsigned u3 = xu[(((unsigned)e3.x & 0xFFFFu) << 6) | c2];
#pragma unroll
        for (int k = 0; k < 4; k++) {
            unsigned u = (k == 0) ? u0 : (k == 1) ? u1 : (k == 2) ? u2 : u3;
            int2 e = (k == 0) ? e0 : (k == 1) ? e1 : (k == 2) ? e2 : e3;
            float lo = __uint_as_float(u << 16);
            float hi = __uint_as_float(u & 0xFFFF0000u);
            float sc = __int_as_float(e.y);
            if ((e.x >> 16) == 0) { spp0 = fmaf(lo, sc, spp0); spp1 = fmaf(hi, sc, spp1); }
            else                  { sgp0 = fmaf(lo, sc, sgp0); sgp1 = fmaf(hi, sc, sgp1); }
        }
    }
    for (; i < end; i += 2) {
        int2 e = edata[i];
        unsigned u = xu[(((unsigned)e.x & 0xFFFFu) << 6) | c2];
        float lo = __uint_as_float(u << 16);
        float hi = __uint_as_float(u & 0xFFFF0000u);
        float sc = __int_as_float(e.y);
        if ((e.x >> 16) == 0) { spp0 = fmaf(lo, sc, spp0); spp1 = fmaf(hi, sc, spp1); }
        else                  { sgp0 = fmaf(lo, sc, sgp0); sgp1 = fmaf(hi, sc, sgp1); }
    }

    __shared__ float red[4][64];
    if (h == 1) { red[0][c2] = spp0; red[1][c2] = spp1; red[2][c2] = sgp0; red[3][c2] = sgp1; }
    __syncthreads();
    if (h == 0) {
        spp0 += red[0][c2]; spp1 += red[1][c2]; sgp0 += red[2][c2]; sgp1 += red[3][c2];
        float ipp = rsqrtf((float)max(indeg_pp[d], 1));
        float igp = rsqrtf((float)max(indeg_gp[d], 1));
        union { unsigned u; __bf16 b[2]; } wp, wg;
        wp.b[0] = (__bf16)(spp0 * ipp); wp.b[1] = (__bf16)(spp1 * ipp);
        wg.b[0] = (__bf16)(sgp0 * igp); wg.b[1] = (__bf16)(sgp1 * igp);
        ((unsigned*)rppb)[((unsigned)d << 6) | c2] = wp.u;
        ((unsigned*)rgpb)[((unsigned)d << 6) | c2] = wg.u;
    }
}

// ---------------- node attention: 2ch/lane uint2 gather, edge-parity waves, unroll-4 ----------------
__global__ __launch_bounds__(128) void node_attn_kernel(const unsigned int* __restrict__ xhl,
                                                        const __bf16* __restrict__ hrb,
                                                        const float* __restrict__ wpp_arr,
                                                        const float* __restrict__ wgp_arr,
                                                        const int* __restrict__ indeg_pg,
                                                        const int* __restrict__ row_ptr,
                                                        const int2* __restrict__ edata,
                                                        __bf16* __restrict__ hb)
{
    const int d = blockIdx.x;
    const int tid = threadIdx.x;
    const unsigned c2 = tid & 63;
    const int h = tid >> 6;
    const int beg = row_ptr[d], end = row_ptr[d + 1];

    unsigned hru = ((const unsigned*)hrb)[((size_t)d << 6) | c2];
    const float hr0 = __uint_as_float(hru << 16);
    const float hr1 = __uint_as_float(hru & 0xFFFF0000u);
    float wp0, wp1, wg0, wg1;
    if (d < NP) {
        float2 wp = ((const float2*)wpp_arr)[((size_t)d << 6) | c2];
        float2 wg = ((const float2*)wgp_arr)[((size_t)d << 6) | c2];
        wp0 = wp.x; wp1 = wp.y; wg0 = wg.x; wg1 = wg.y;
    } else {
        float w = 1.f / (float)max(indeg_pg[d - NP], 1);
        wp0 = wp1 = wg0 = wg1 = w;
    }
    float ssum0 = 0.f, ssum1 = 0.f, acc0 = 0.f, acc1 = 0.f;
    const uint2* xp = (const uint2*)xhl;

    auto body = [&](int p, uint2 u) {
        bool pp = (p >> 16) == 0;
        float a0 = pp ? wp0 : wg0;
        float a1 = pp ? wp1 : wg1;
        float x0  = __uint_as_float(u.x << 16);
        float hl0 = __uint_as_float(u.x & 0xFFFF0000u);
        float x1  = __uint_as_float(u.y << 16);
        float hl1 = __uint_as_float(u.y & 0xFFFF0000u);
        float e0 = (hl0 + hr0) * a0; e0 = fmaxf(e0, -0.2f * e0);
        float e1 = (hl1 + hr1) * a1; e1 = fmaxf(e1, -0.2f * e1);
        float p0 = __expf(e0), p1 = __expf(e1);
        ssum0 += p0; ssum1 += p1;
        acc0 = fmaf(p0, x0, acc0);
        acc1 = fmaf(p1, x1, acc1);
    };

    int i = beg + h;
    for (; i + 6 < end; i += 8) {
        int p0 = edata[i].x, p1 = edata[i + 2].x, p2 = edata[i + 4].x, p3 = edata[i + 6].x;
        uint2 u0 = xp[(((unsigned)p0 & 0xFFFFu) << 6) | c2];
        uint2 u1 = xp[(((unsigned)p1 & 0xFFFFu) << 6) | c2];
        uint2 u2 = xp[(((unsigned)p2 & 0xFFFFu) << 6) | c2];
        uint2 u3 = xp[(((unsigned)p3 & 0xFFFFu) << 6) | c2];
        body(p0, u0); body(p1, u1); body(p2, u2); body(p3, u3);
    }
    for (; i < end; i += 2) {
        int p = edata[i].x;
        uint2 u = xp[(((unsigned)p & 0xFFFFu) << 6) | c2];
        body(p, u);
    }

    __shared__ float red[4][64];
    if (h == 1) { red[0][c2] = ssum0; red[1][c2] = ssum1; red[2][c2] = acc0; red[3][c2] = acc1; }
    __syncthreads();
    if (h == 0) {
        ssum0 += red[0][c2]; ssum1 += red[1][c2];
        acc0 += red[2][c2];  acc1 += red[3][c2];
        float o0 = (end > beg) ? acc0 / ssum0 : 0.f;
        float o1 = (end > beg) ? acc1 / ssum1 : 0.f;
        union { unsigned u; __bf16 b[2]; } o;
        o.b[0] = (__bf16)o0; o.b[1] = (__bf16)o1;
        ((unsigned*)hb)[((size_t)d << 6) | c2] = o.u;
    }
}

extern "C" void kernel_launch(void* const* d_in, const int* in_sizes, int n_in,
                              void* d_out, int out_size, void* d_ws, size_t ws_size,
                              hipStream_t stream)
{
    const float* x_protein = (const float*)d_in[0];
    const float* x_go      = (const float*)d_in[1];
    const int* src_pp = (const int*)d_in[2];
    const int* dst_pp = (const int*)d_in[3];
    const int* src_pg = (const int*)d_in[4];
    const int* dst_pg = (const int*)d_in[5];
    const int* src_gp = (const int*)d_in[6];
    const int* dst_gp = (const int*)d_in[7];
    const float* W1p = (const float*)d_in[8];
    const float* b1p = (const float*)d_in[9];
    const float* W1g = (const float*)d_in[10];
    const float* b1g = (const float*)d_in[11];
    const float* Wl_p = (const float*)d_in[12];
    const float* bl_p = (const float*)d_in[13];
    // Wl_g (14), bl_g (15) dead: go-dst type-alpha is uniform 1/n
    const float* Wr_p = (const float*)d_in[16];
    const float* br_p = (const float*)d_in[17];
    const float* Wr_g = (const float*)d_in[18];
    const float* br_g = (const float*)d_in[19];
    const float* Wnl = (const float*)d_in[20];
    const float* bnl = (const float*)d_in[21];
    const float* Wnr = (const float*)d_in[22];
    const float* bnr = (const float*)d_in[23];
    const float* Wfc = (const float*)d_in[24];
    const float* bfc = (const float*)d_in[25];
    float* out = (float*)d_out;

    // ---- workspace layout (4B words); total ~63 MB ----
    size_t off = 0;
    char* base = (char*)d_ws;
    auto alloc = [&](size_t words) { void* p = base + off * 4; off += (words + 7) & ~(size_t)7; return p; };

    __bf16* xb  = (__bf16*)alloc((size_t)25024 * 128 / 2);
    __bf16* hrb = (__bf16*)alloc((size_t)25024 * 128 / 2);
    // U region: rppb+rgpb until ea_wa; xhl after (hlr writes it)
    char* U = (char*)alloc((size_t)25024 * 128);
    __bf16* rppb = (__bf16*)U;
    __bf16* rgpb = (__bf16*)(U + (size_t)20032 * 128 * 2);
    unsigned int* xhl = (unsigned int*)U;
    // R1: hist partials -> xgb -> (wpp, wgp, haggb)
    char* R1 = (char*)alloc((size_t)5128192 + 2588672);
    int*    partial = (int*)R1;
    __bf16* xgb = (__bf16*)R1;
    float*  wpp = (float*)R1;
    float*  wgp = wpp + (size_t)20000 * 128;
    __bf16* haggb = (__bf16*)(wgp + (size_t)20000 * 128);
    __bf16* w1pt = (__bf16*)alloc(128 * 512 / 2);
    __bf16* w1gt = (__bf16*)alloc(128 * 1024 / 2);
    __bf16* wlpt = (__bf16*)alloc(128 * 128 / 2);
    __bf16* wrpt = (__bf16*)alloc(128 * 128 / 2);
    __bf16* wrgt = (__bf16*)alloc(128 * 128 / 2);
    __bf16* wnlt = (__bf16*)alloc(128 * 128 / 2);
    __bf16* wnrt = (__bf16*)alloc(128 * 128 / 2);
    __bf16* wfct = (__bf16*)alloc(1024 * 128 / 2);
    int* outdeg_pp = (int*)alloc(NP);
    int* outdeg_pg = (int*)alloc(NP);
    int* outdeg_gp = (int*)alloc(NG);
    int* indeg_pp  = (int*)alloc(NP);
    int* indeg_gp  = (int*)alloc(NP);
    int* indeg_pg  = (int*)alloc(NG);
    int* fill      = (int*)alloc((size_t)NTOT * FS);
    int* row_ptr   = (int*)alloc(NTOT + 1);
    int2* edata    = (int2*)alloc((size_t)ETOT * 2);

    // 1) degree histograms (partial, LDS-private)
    hist_part_kernel<<<dim3(HB, 6), 1024, 0, stream>>>(
        src_pp, dst_pp, src_pg, dst_pg, src_gp, dst_gp, partial);
    // 2) merge partials + zero fill counters (job 6)
    hist_merge_kernel<<<dim3((NTOT * FS + 255) / 256, 7), 256, 0, stream>>>(
        partial, outdeg_pp, indeg_pp, outdeg_pg, indeg_pg, outdeg_gp, indeg_gp, fill);
    // 3) row_ptr scan
    scan_kernel<<<1, 1024, 0, stream>>>(indeg_pp, indeg_gp, indeg_pg, row_ptr);
    // 4) fused CSR scatter + all conversions (overlapped in one launch)
    scatter_conv_kernel<<<SCB + 4128, 256, 0, stream>>>(
        src_pp, dst_pp, src_pg, dst_pg, src_gp, dst_gp,
        outdeg_pp, outdeg_pg, outdeg_gp, row_ptr, fill, edata,
        x_go, W1p, W1g, Wl_p, Wr_p, Wr_g, Wnl, Wnr, Wfc,
        xgb, w1pt, w1gt, wlpt, wrpt, wrgt, wnlt, wnrt, wfct);

    // 5) fused projections + l2norm -> xb (bf16); protein A = fp32 direct
    {
        GJob p0 = { x_protein, w1pt, nullptr, b1p, nullptr, nullptr, nullptr, nullptr, xb,
                    NP, 128, 512, 16, 1 };
        GJob p1 = { xgb, w1gt, nullptr, b1g, nullptr, nullptr, nullptr, nullptr,
                    xb + (size_t)NP * 128, NG, 128, 1024, 32, 0 };
        gemm_bt<2, 0, 2><<<392, 256, 0, stream>>>(p0, p1, 313);
    }

    // 6) GCN aggregation for type attention (protein dst only) — dword gather
    rst_agg_kernel<<<NP, 128, 0, stream>>>(xb, row_ptr, edata, indeg_pp, indeg_gp, rppb, rgpb);

    // 7) fused ea + type-softmax weights -> wpp/wgp (fp32); rppb/rgpb dead after this
    ea_wa_kernel<<<313, 256, 0, stream>>>(xb, rppb, rgpb, wlpt, wrpt, wrgt,
                                          bl_p, br_p, br_g, indeg_pp, indeg_gp, wpp, wgp);

    // 8) node attention projections: packed xhl {x, hl} + hr (bf16 dense)
    {
        GJob h0 = { xb, wnlt, wnrt, bnl, bnr, nullptr, hrb, xhl, nullptr,
                    NTOT, 128, 128, 4, 0 };
        gemm_bt<0, 1, 3><<<391, 256, 0, stream>>>(h0, h0, 1 << 30);
    }

    // 9) node attention + aggregation -> haggb
    node_attn_kernel<<<NTOT, 128, 0, stream>>>(xhl, hrb, wpp, wgp, indeg_pg, row_ptr, edata, haggb);

    // 10) final classifier: out = hagg@Wfc + bfc
    {
        GJob o0 = { haggb, wfct, nullptr, bfc, nullptr, out, nullptr, nullptr, nullptr,
                    NTOT, NCLS, 128, 4, 0 };
        gemm_bt<0, 0, 0><<<dim3(391, 8), 256, 0, stream>>>(o0, o0, 1 << 30);
    }

    (void)in_sizes; (void)n_in; (void)out_size; (void)ws_size;
}